// Round 7
// baseline (740.135 us; speedup 1.0000x reference)
//
#include <hip/hip_runtime.h>
#include <hip/hip_bf16.h>

typedef unsigned int uint;

// B=16, H=2048, NH=16, HD=128, S=4096, 3H=6144, FF=8192. All tensors f32.

// ---------------- LayerNorm (f32) ----------------
__global__ __launch_bounds__(256) void ln_f32_kernel(const float* __restrict__ in,
    const float* __restrict__ g, const float* __restrict__ bb, float* __restrict__ out)
{
    int row = blockIdx.x, t = threadIdx.x;
    const float* rp = in + row*2048;
    float4 a = ((const float4*)rp)[2*t];
    float4 b = ((const float4*)rp)[2*t+1];
    float v[8] = {a.x,a.y,a.z,a.w,b.x,b.y,b.z,b.w};
    float s=0.f, s2=0.f;
    #pragma unroll
    for(int i=0;i<8;i++){ s+=v[i]; s2+=v[i]*v[i]; }
    #pragma unroll
    for(int o=32;o>0;o>>=1){ s += __shfl_xor(s,o); s2 += __shfl_xor(s2,o); }
    __shared__ float red[8];
    int wv=t>>6, ln=t&63;
    if(ln==0){ red[wv]=s; red[4+wv]=s2; }
    __syncthreads();
    s  = red[0]+red[1]+red[2]+red[3];
    s2 = red[4]+red[5]+red[6]+red[7];
    float mu = s*(1.f/2048.f);
    float var = s2*(1.f/2048.f) - mu*mu;
    float rs = rsqrtf(var + 1e-5f);
    float4 g0 = ((const float4*)g)[2*t],  g1 = ((const float4*)g)[2*t+1];
    float4 b0 = ((const float4*)bb)[2*t], b1 = ((const float4*)bb)[2*t+1];
    float* op = out + row*2048 + t*8;
    float4 o0 = make_float4((v[0]-mu)*rs*g0.x+b0.x, (v[1]-mu)*rs*g0.y+b0.y,
                            (v[2]-mu)*rs*g0.z+b0.z, (v[3]-mu)*rs*g0.w+b0.w);
    float4 o1 = make_float4((v[4]-mu)*rs*g1.x+b1.x, (v[5]-mu)*rs*g1.y+b1.y,
                            (v[6]-mu)*rs*g1.z+b1.z, (v[7]-mu)*rs*g1.w+b1.w);
    ((float4*)op)[0]=o0; ((float4*)op)[1]=o1;
}

// ---------------- split-K skinny GEMM: part[kc][16][N] = X[16,K] * W[K,N] ----------------
template<int KCHUNK>
__global__ __launch_bounds__(256) void gemm_sk(const float* __restrict__ X,
    const float* __restrict__ W, float* __restrict__ part, int K, int N, int colchunks)
{
    __shared__ float XS[16][KCHUNK];
    int cc = blockIdx.x % colchunks;
    int kc = blockIdx.x / colchunks;
    int k0 = kc * KCHUNK;
    for (int idx = threadIdx.x; idx < 16*KCHUNK; idx += 256){
        int m = idx / KCHUNK, i = idx % KCHUNK;
        XS[m][i] = X[m*K + k0 + i];
    }
    __syncthreads();
    int n0 = cc*512 + threadIdx.x*2;
    float a0[16], a1[16];
    #pragma unroll
    for(int m=0;m<16;m++){ a0[m]=0.f; a1[m]=0.f; }
    const float* Wp = W + (size_t)k0*N + n0;
    for (int i=0;i<KCHUNK;i+=4){
        float2 w0 = *(const float2*)(Wp + (size_t)(i+0)*N);
        float2 w1 = *(const float2*)(Wp + (size_t)(i+1)*N);
        float2 w2 = *(const float2*)(Wp + (size_t)(i+2)*N);
        float2 w3 = *(const float2*)(Wp + (size_t)(i+3)*N);
        #pragma unroll
        for(int m=0;m<16;m++){
            float4 x4 = *(const float4*)&XS[m][i];
            a0[m] += x4.x*w0.x + x4.y*w1.x + x4.z*w2.x + x4.w*w3.x;
            a1[m] += x4.x*w0.y + x4.y*w1.y + x4.z*w2.y + x4.w*w3.y;
        }
    }
    #pragma unroll
    for(int m=0;m<16;m++){
        *(float2*)&part[((size_t)(kc*16+m))*N + n0] = make_float2(a0[m], a1[m]);
    }
}

// ---------------- split-K reduce + bias + (residual / gelu / store) ----------------
__global__ __launch_bounds__(256) void reduce_sk(const float* __restrict__ part, int N, int splitk,
    const float* __restrict__ bias, const float* __restrict__ res,
    float* __restrict__ outf, int mode)
{
    int n = blockIdx.x*256 + threadIdx.x;
    int m = blockIdx.y;
    size_t stride = (size_t)16*N;
    const float* p = part + (size_t)m*N + n;
    float s = 0.f;
    for (int kc=0;kc<splitk;kc++) s += p[(size_t)kc*stride];
    s += bias[n];
    if (mode==1 || mode==3) s += res[m*N+n];
    if (mode==2){
        float x = s;
        float t = tanhf(0.7978845608028654f*(x + 0.044715f*x*x*x));
        s = 0.5f*x*(1.f+t);
    }
    outf[m*N+n] = s;
}

// ---------------- flash-decode attention, phase-split K then V (R4 version, unchanged) ----------------
__global__ __launch_bounds__(256) void attn_chunk(const float* __restrict__ qkv,
    const float* __restrict__ Kc, const float* __restrict__ Vc, float* __restrict__ part)
{
    int h = blockIdx.y, b = blockIdx.z;
    int wave = threadIdx.x >> 6, lane = threadIdx.x & 63;
    int wc = blockIdx.x*4 + wave;            // 0..31
    int grp = lane >> 4, cl = lane & 15;
    const float* qrow = qkv + b*6144 + h*128 + cl*8;
    float4 qa = *(const float4*)qrow;
    float4 qb = *(const float4*)(qrow + 4);
    size_t bh = (size_t)(b*16+h);
    size_t base = bh*524288 + (size_t)wc*16384 + (size_t)grp*128 + cl*8;
    const float* Kp = Kc + base;
    const float* Vp = Vc + base;

    float s[32];
    #pragma unroll
    for (int i=0;i<32;i++){
        const float* kp = Kp + (size_t)i*512;
        float4 ka = *(const float4*)kp;
        float4 kb = *(const float4*)(kp + 4);
        float p = qa.x*ka.x + qa.y*ka.y + qa.z*ka.z + qa.w*ka.w
                + qb.x*kb.x + qb.y*kb.y + qb.z*kb.z + qb.w*kb.w;
        p += __shfl_xor(p,1); p += __shfl_xor(p,2);
        p += __shfl_xor(p,4); p += __shfl_xor(p,8);
        s[i] = p * 0.08838834764831845f;
    }
    float m = s[0];
    #pragma unroll
    for (int i=1;i<32;i++) m = fmaxf(m, s[i]);
    m = fmaxf(m, __shfl_xor(m,16));
    m = fmaxf(m, __shfl_xor(m,32));

    float sn = 0.f;
    if (wc == 31){
        const float* kn = qkv + b*6144 + 2048 + h*128 + cl*8;
        float4 ka = *(const float4*)kn, kb = *(const float4*)(kn+4);
        float p = qa.x*ka.x + qa.y*ka.y + qa.z*ka.z + qa.w*ka.w
                + qb.x*kb.x + qb.y*kb.y + qb.z*kb.z + qb.w*kb.w;
        p += __shfl_xor(p,1); p += __shfl_xor(p,2);
        p += __shfl_xor(p,4); p += __shfl_xor(p,8);
        sn = p * 0.08838834764831845f;
        m = fmaxf(m, sn);
    }

    float l = 0.f;
    #pragma unroll
    for (int i=0;i<32;i++){ s[i] = __expf(s[i] - m); l += s[i]; }

    float o[8];
    #pragma unroll
    for (int i=0;i<8;i++) o[i] = 0.f;
    #pragma unroll
    for (int i=0;i<32;i++){
        const float* vp = Vp + (size_t)i*512;
        float4 va = *(const float4*)vp;
        float4 vb = *(const float4*)(vp + 4);
        float e = s[i];
        o[0]+=e*va.x; o[1]+=e*va.y; o[2]+=e*va.z; o[3]+=e*va.w;
        o[4]+=e*vb.x; o[5]+=e*vb.y; o[6]+=e*vb.z; o[7]+=e*vb.w;
    }
    if (wc == 31){
        const float* vn = qkv + b*6144 + 4096 + h*128 + cl*8;
        float4 va = *(const float4*)vn, vb = *(const float4*)(vn+4);
        float e = (grp==0) ? __expf(sn - m) : 0.f;
        l += e;
        o[0]+=e*va.x; o[1]+=e*va.y; o[2]+=e*va.z; o[3]+=e*va.w;
        o[4]+=e*vb.x; o[5]+=e*vb.y; o[6]+=e*vb.z; o[7]+=e*vb.w;
    }

    l += __shfl_xor(l,16); l += __shfl_xor(l,32);
    #pragma unroll
    for(int i=0;i<8;i++){ o[i] += __shfl_xor(o[i],16); o[i] += __shfl_xor(o[i],32); }
    float* pp = part + ((size_t)bh*32 + wc)*136;
    if (lane==0){ pp[0]=m; pp[1]=l; }
    if (lane<16){
        *(float4*)&pp[4 + lane*8]     = make_float4(o[0],o[1],o[2],o[3]);
        *(float4*)&pp[4 + lane*8 + 4] = make_float4(o[4],o[5],o[6],o[7]);
    }
}

__global__ __launch_bounds__(64) void attn_combine(const float* __restrict__ part,
                                                   float* __restrict__ attn_out)
{
    int bh = blockIdx.x;      // 0..255
    int lane = threadIdx.x;   // 64
    const float* pp = part + (size_t)bh*32*136;
    float M = -1e30f;
    for (int kc=0;kc<32;kc++) M = fmaxf(M, pp[kc*136]);
    float den=0.f, a0=0.f, a1=0.f;
    for (int kc=0;kc<32;kc++){
        float f = __expf(pp[kc*136] - M);
        den += f * pp[kc*136+1];
        float2 o = *(const float2*)&pp[kc*136 + 4 + 2*lane];
        a0 += f*o.x; a1 += f*o.y;
    }
    float inv = 1.f/den;
    int b = bh>>4, h = bh&15;
    float* op = attn_out + b*2048 + h*128 + 2*lane;
    op[0]=a0*inv; op[1]=a1*inv;
}

// ---------------- PROBE: textbook grid-stride dense read of K then V, x2 passes ----------------
// 2048 blocks x 256 thr. Reads 2x(537+537)MB = 2.14 GB -> guaranteed top-5 in rocprof,
// giving a DIRECT hbm_gbps reading for a pure read-only stream (H1 vs H2 test).
// Writes 2MB into dead gpart scratch (after d_out is final).
__global__ __launch_bounds__(256) void probe_dense(const float* __restrict__ Kc,
    const float* __restrict__ Vc, float* __restrict__ sink)
{
    const size_t NT = (size_t)2048*256;
    size_t tid = (size_t)blockIdx.x*256 + threadIdx.x;
    const size_t N4 = 33554432;   // 16*16*4096*128 / 4 float4s per tensor
    float acc = 0.f;
    #pragma unroll 1
    for (int pass=0; pass<2; ++pass){
        for (size_t i=tid; i<N4; i+=NT){
            float4 k = ((const float4*)Kc)[i];
            acc += k.x+k.y+k.z+k.w;
        }
        for (size_t i=tid; i<N4; i+=NT){
            float4 v = ((const float4*)Vc)[i];
            acc += v.x+v.y+v.z+v.w;
        }
    }
    sink[tid] = acc;
}

extern "C" void kernel_launch(void* const* d_in, const int* in_sizes, int n_in,
                              void* d_out, int out_size, void* d_ws, size_t ws_size,
                              hipStream_t stream)
{
    const float* hid  = (const float*)d_in[0];
    const float* Kc   = (const float*)d_in[1];
    const float* Vc   = (const float*)d_in[2];
    const float* ln1g = (const float*)d_in[3];
    const float* ln1b = (const float*)d_in[4];
    const float* Wqkv = (const float*)d_in[5];
    const float* bqkv = (const float*)d_in[6];
    const float* Wproj= (const float*)d_in[7];
    const float* bproj= (const float*)d_in[8];
    const float* ln2g = (const float*)d_in[9];
    const float* ln2b = (const float*)d_in[10];
    const float* Wfc  = (const float*)d_in[11];
    const float* bfc  = (const float*)d_in[12];
    const float* Wout = (const float*)d_in[13];
    const float* bout = (const float*)d_in[14];

    float* ws      = (float*)d_ws;
    float* xln     = ws;                    // 32768
    float* qkv     = xln + 32768;           // 98304
    float* attn_o  = qkv + 98304;           // 32768
    float* hbuf    = attn_o + 32768;        // 32768
    float* yln     = hbuf + 32768;          // 32768
    float* act     = yln + 32768;           // 131072
    float* apart   = act + 131072;          // 16*16*32*136 = 1114112
    float* gpart   = apart + 1114112;       // up to 3145728 (QKV partials)

    // 1. LN1
    ln_f32_kernel<<<16,256,0,stream>>>(hid, ln1g, ln1b, xln);
    // 2. QKV = xln @ Wqkv + b   (K=2048, N=6144, splitk=32)
    gemm_sk<64><<<12*32,256,0,stream>>>(xln, Wqkv, gpart, 2048, 6144, 12);
    reduce_sk<<<dim3(24,16),256,0,stream>>>(gpart, 6144, 32, bqkv, nullptr, qkv, 0);
    // 3. attention
    attn_chunk<<<dim3(8,16,16),256,0,stream>>>(qkv, Kc, Vc, apart);
    attn_combine<<<256,64,0,stream>>>(apart, attn_o);
    // 4. proj + residual (K=2048, N=2048, splitk=32)
    gemm_sk<64><<<4*32,256,0,stream>>>(attn_o, Wproj, gpart, 2048, 2048, 4);
    reduce_sk<<<dim3(8,16),256,0,stream>>>(gpart, 2048, 32, bproj, hid, hbuf, 1);
    // 5. LN2
    ln_f32_kernel<<<16,256,0,stream>>>(hbuf, ln2g, ln2b, yln);
    // 6. FC + gelu (K=2048, N=8192, splitk=32)
    gemm_sk<64><<<16*32,256,0,stream>>>(yln, Wfc, gpart, 2048, 8192, 16);
    reduce_sk<<<dim3(32,16),256,0,stream>>>(gpart, 8192, 32, bfc, nullptr, act, 2);
    // 7. OUT + residual -> f32 d_out (K=8192, N=2048, splitk=64, kchunk=128)
    gemm_sk<128><<<4*64,256,0,stream>>>(act, Wout, gpart, 8192, 2048, 4);
    reduce_sk<<<dim3(8,16),256,0,stream>>>(gpart, 2048, 64, bout, hbuf, (float*)d_out, 3);
    // 8. PROBE (after d_out final; writes dead gpart scratch)
    probe_dense<<<2048,256,0,stream>>>(Kc, Vc, gpart);
    (void)in_sizes; (void)n_in; (void)out_size; (void)ws_size;
}

// Round 9
// 452.684 us; speedup vs baseline: 1.6350x; 1.6350x over previous
//
#include <hip/hip_runtime.h>
#include <hip/hip_bf16.h>

typedef unsigned int uint;
typedef float vf4 __attribute__((ext_vector_type(4)));
typedef float vf2 __attribute__((ext_vector_type(2)));

#define DEV static __device__ __forceinline__

// Nontemporal (cache-bypass) loads for streaming data — native clang vector types
DEV vf4 nt4(const float* p){ return __builtin_nontemporal_load((const vf4*)p); }
DEV vf2 nt2(const float* p){ return __builtin_nontemporal_load((const vf2*)p); }

// B=16, H=2048, NH=16, HD=128, S=4096, 3H=6144, FF=8192. All tensors f32.

// ---------------- LayerNorm (f32) ----------------
__global__ __launch_bounds__(256) void ln_f32_kernel(const float* __restrict__ in,
    const float* __restrict__ g, const float* __restrict__ bb, float* __restrict__ out)
{
    int row = blockIdx.x, t = threadIdx.x;
    const float* rp = in + row*2048;
    float4 a = ((const float4*)rp)[2*t];
    float4 b = ((const float4*)rp)[2*t+1];
    float v[8] = {a.x,a.y,a.z,a.w,b.x,b.y,b.z,b.w};
    float s=0.f, s2=0.f;
    #pragma unroll
    for(int i=0;i<8;i++){ s+=v[i]; s2+=v[i]*v[i]; }
    #pragma unroll
    for(int o=32;o>0;o>>=1){ s += __shfl_xor(s,o); s2 += __shfl_xor(s2,o); }
    __shared__ float red[8];
    int wv=t>>6, ln=t&63;
    if(ln==0){ red[wv]=s; red[4+wv]=s2; }
    __syncthreads();
    s  = red[0]+red[1]+red[2]+red[3];
    s2 = red[4]+red[5]+red[6]+red[7];
    float mu = s*(1.f/2048.f);
    float var = s2*(1.f/2048.f) - mu*mu;
    float rs = rsqrtf(var + 1e-5f);
    float4 g0 = ((const float4*)g)[2*t],  g1 = ((const float4*)g)[2*t+1];
    float4 b0 = ((const float4*)bb)[2*t], b1 = ((const float4*)bb)[2*t+1];
    float* op = out + row*2048 + t*8;
    float4 o0 = make_float4((v[0]-mu)*rs*g0.x+b0.x, (v[1]-mu)*rs*g0.y+b0.y,
                            (v[2]-mu)*rs*g0.z+b0.z, (v[3]-mu)*rs*g0.w+b0.w);
    float4 o1 = make_float4((v[4]-mu)*rs*g1.x+b1.x, (v[5]-mu)*rs*g1.y+b1.y,
                            (v[6]-mu)*rs*g1.z+b1.z, (v[7]-mu)*rs*g1.w+b1.w);
    ((float4*)op)[0]=o0; ((float4*)op)[1]=o1;
}

// ---------------- split-K skinny GEMM: part[kc][16][N] = X[16,K] * W[K,N] ----------------
// Weight loads are nontemporal (read-once stream, no reuse within dispatch).
template<int KCHUNK>
__global__ __launch_bounds__(256) void gemm_sk(const float* __restrict__ X,
    const float* __restrict__ W, float* __restrict__ part, int K, int N, int colchunks)
{
    __shared__ float XS[16][KCHUNK];
    int cc = blockIdx.x % colchunks;
    int kc = blockIdx.x / colchunks;
    int k0 = kc * KCHUNK;
    for (int idx = threadIdx.x; idx < 16*KCHUNK; idx += 256){
        int m = idx / KCHUNK, i = idx % KCHUNK;
        XS[m][i] = X[m*K + k0 + i];
    }
    __syncthreads();
    int n0 = cc*512 + threadIdx.x*2;
    float a0[16], a1[16];
    #pragma unroll
    for(int m=0;m<16;m++){ a0[m]=0.f; a1[m]=0.f; }
    const float* Wp = W + (size_t)k0*N + n0;
    for (int i=0;i<KCHUNK;i+=4){
        vf2 w0 = nt2(Wp + (size_t)(i+0)*N);
        vf2 w1 = nt2(Wp + (size_t)(i+1)*N);
        vf2 w2 = nt2(Wp + (size_t)(i+2)*N);
        vf2 w3 = nt2(Wp + (size_t)(i+3)*N);
        #pragma unroll
        for(int m=0;m<16;m++){
            float4 x4 = *(const float4*)&XS[m][i];
            a0[m] += x4.x*w0.x + x4.y*w1.x + x4.z*w2.x + x4.w*w3.x;
            a1[m] += x4.x*w0.y + x4.y*w1.y + x4.z*w2.y + x4.w*w3.y;
        }
    }
    #pragma unroll
    for(int m=0;m<16;m++){
        *(float2*)&part[((size_t)(kc*16+m))*N + n0] = make_float2(a0[m], a1[m]);
    }
}

// ---------------- split-K reduce + bias + (residual / gelu / store) ----------------
__global__ __launch_bounds__(256) void reduce_sk(const float* __restrict__ part, int N, int splitk,
    const float* __restrict__ bias, const float* __restrict__ res,
    float* __restrict__ outf, int mode)
{
    int n = blockIdx.x*256 + threadIdx.x;
    int m = blockIdx.y;
    size_t stride = (size_t)16*N;
    const float* p = part + (size_t)m*N + n;
    float s = 0.f;
    for (int kc=0;kc<splitk;kc++) s += p[(size_t)kc*stride];
    s += bias[n];
    if (mode==1 || mode==3) s += res[m*N+n];
    if (mode==2){
        float x = s;
        float t = tanhf(0.7978845608028654f*(x + 0.044715f*x*x*x));
        s = 0.5f*x*(1.f+t);
    }
    outf[m*N+n] = s;
}

// ---------------- flash-decode attention, phase-split K then V, NT loads on K/V ----------------
__global__ __launch_bounds__(256) void attn_chunk(const float* __restrict__ qkv,
    const float* __restrict__ Kc, const float* __restrict__ Vc, float* __restrict__ part)
{
    int h = blockIdx.y, b = blockIdx.z;
    int wave = threadIdx.x >> 6, lane = threadIdx.x & 63;
    int wc = blockIdx.x*4 + wave;            // 0..31
    int grp = lane >> 4, cl = lane & 15;
    const float* qrow = qkv + b*6144 + h*128 + cl*8;
    float4 qa = *(const float4*)qrow;
    float4 qb = *(const float4*)(qrow + 4);
    size_t bh = (size_t)(b*16+h);
    size_t base = bh*524288 + (size_t)wc*16384 + (size_t)grp*128 + cl*8;
    const float* Kp = Kc + base;
    const float* Vp = Vc + base;

    float s[32];
    #pragma unroll
    for (int i=0;i<32;i++){
        const float* kp = Kp + (size_t)i*512;
        vf4 ka = nt4(kp);
        vf4 kb = nt4(kp + 4);
        float p = qa.x*ka.x + qa.y*ka.y + qa.z*ka.z + qa.w*ka.w
                + qb.x*kb.x + qb.y*kb.y + qb.z*kb.z + qb.w*kb.w;
        p += __shfl_xor(p,1); p += __shfl_xor(p,2);
        p += __shfl_xor(p,4); p += __shfl_xor(p,8);
        s[i] = p * 0.08838834764831845f;
    }
    float m = s[0];
    #pragma unroll
    for (int i=1;i<32;i++) m = fmaxf(m, s[i]);
    m = fmaxf(m, __shfl_xor(m,16));
    m = fmaxf(m, __shfl_xor(m,32));

    float sn = 0.f;
    if (wc == 31){
        const float* kn = qkv + b*6144 + 2048 + h*128 + cl*8;
        float4 ka = *(const float4*)kn, kb = *(const float4*)(kn+4);
        float p = qa.x*ka.x + qa.y*ka.y + qa.z*ka.z + qa.w*ka.w
                + qb.x*kb.x + qb.y*kb.y + qb.z*kb.z + qb.w*kb.w;
        p += __shfl_xor(p,1); p += __shfl_xor(p,2);
        p += __shfl_xor(p,4); p += __shfl_xor(p,8);
        sn = p * 0.08838834764831845f;
        m = fmaxf(m, sn);
    }

    float l = 0.f;
    #pragma unroll
    for (int i=0;i<32;i++){ s[i] = __expf(s[i] - m); l += s[i]; }

    float o[8];
    #pragma unroll
    for (int i=0;i<8;i++) o[i] = 0.f;
    #pragma unroll
    for (int i=0;i<32;i++){
        const float* vp = Vp + (size_t)i*512;
        vf4 va = nt4(vp);
        vf4 vb = nt4(vp + 4);
        float e = s[i];
        o[0]+=e*va.x; o[1]+=e*va.y; o[2]+=e*va.z; o[3]+=e*va.w;
        o[4]+=e*vb.x; o[5]+=e*vb.y; o[6]+=e*vb.z; o[7]+=e*vb.w;
    }
    if (wc == 31){
        const float* vn = qkv + b*6144 + 4096 + h*128 + cl*8;
        float4 va = *(const float4*)vn, vb = *(const float4*)(vn+4);
        float e = (grp==0) ? __expf(sn - m) : 0.f;
        l += e;
        o[0]+=e*va.x; o[1]+=e*va.y; o[2]+=e*va.z; o[3]+=e*va.w;
        o[4]+=e*vb.x; o[5]+=e*vb.y; o[6]+=e*vb.z; o[7]+=e*vb.w;
    }

    l += __shfl_xor(l,16); l += __shfl_xor(l,32);
    #pragma unroll
    for(int i=0;i<8;i++){ o[i] += __shfl_xor(o[i],16); o[i] += __shfl_xor(o[i],32); }
    float* pp = part + ((size_t)bh*32 + wc)*136;
    if (lane==0){ pp[0]=m; pp[1]=l; }
    if (lane<16){
        *(float4*)&pp[4 + lane*8]     = make_float4(o[0],o[1],o[2],o[3]);
        *(float4*)&pp[4 + lane*8 + 4] = make_float4(o[4],o[5],o[6],o[7]);
    }
}

__global__ __launch_bounds__(64) void attn_combine(const float* __restrict__ part,
                                                   float* __restrict__ attn_out)
{
    int bh = blockIdx.x;      // 0..255
    int lane = threadIdx.x;   // 64
    const float* pp = part + (size_t)bh*32*136;
    float M = -1e30f;
    for (int kc=0;kc<32;kc++) M = fmaxf(M, pp[kc*136]);
    float den=0.f, a0=0.f, a1=0.f;
    for (int kc=0;kc<32;kc++){
        float f = __expf(pp[kc*136] - M);
        den += f * pp[kc*136+1];
        float2 o = *(const float2*)&pp[kc*136 + 4 + 2*lane];
        a0 += f*o.x; a1 += f*o.y;
    }
    float inv = 1.f/den;
    int b = bh>>4, h = bh&15;
    float* op = attn_out + b*2048 + h*128 + 2*lane;
    op[0]=a0*inv; op[1]=a1*inv;
}

extern "C" void kernel_launch(void* const* d_in, const int* in_sizes, int n_in,
                              void* d_out, int out_size, void* d_ws, size_t ws_size,
                              hipStream_t stream)
{
    const float* hid  = (const float*)d_in[0];
    const float* Kc   = (const float*)d_in[1];
    const float* Vc   = (const float*)d_in[2];
    const float* ln1g = (const float*)d_in[3];
    const float* ln1b = (const float*)d_in[4];
    const float* Wqkv = (const float*)d_in[5];
    const float* bqkv = (const float*)d_in[6];
    const float* Wproj= (const float*)d_in[7];
    const float* bproj= (const float*)d_in[8];
    const float* ln2g = (const float*)d_in[9];
    const float* ln2b = (const float*)d_in[10];
    const float* Wfc  = (const float*)d_in[11];
    const float* bfc  = (const float*)d_in[12];
    const float* Wout = (const float*)d_in[13];
    const float* bout = (const float*)d_in[14];

    float* ws      = (float*)d_ws;
    float* xln     = ws;                    // 32768
    float* qkv     = xln + 32768;           // 98304
    float* attn_o  = qkv + 98304;           // 32768
    float* hbuf    = attn_o + 32768;        // 32768
    float* yln     = hbuf + 32768;          // 32768
    float* act     = yln + 32768;           // 131072
    float* apart   = act + 131072;          // 16*16*32*136 = 1114112
    float* gpart   = apart + 1114112;       // up to 3145728 (QKV partials)

    // 1. LN1
    ln_f32_kernel<<<16,256,0,stream>>>(hid, ln1g, ln1b, xln);
    // 2. QKV = xln @ Wqkv + b   (K=2048, N=6144, splitk=32)
    gemm_sk<64><<<12*32,256,0,stream>>>(xln, Wqkv, gpart, 2048, 6144, 12);
    reduce_sk<<<dim3(24,16),256,0,stream>>>(gpart, 6144, 32, bqkv, nullptr, qkv, 0);
    // 3. attention
    attn_chunk<<<dim3(8,16,16),256,0,stream>>>(qkv, Kc, Vc, apart);
    attn_combine<<<256,64,0,stream>>>(apart, attn_o);
    // 4. proj + residual (K=2048, N=2048, splitk=32)
    gemm_sk<64><<<4*32,256,0,stream>>>(attn_o, Wproj, gpart, 2048, 2048, 4);
    reduce_sk<<<dim3(8,16),256,0,stream>>>(gpart, 2048, 32, bproj, hid, hbuf, 1);
    // 5. LN2
    ln_f32_kernel<<<16,256,0,stream>>>(hbuf, ln2g, ln2b, yln);
    // 6. FC + gelu (K=2048, N=8192, splitk=32)
    gemm_sk<64><<<16*32,256,0,stream>>>(yln, Wfc, gpart, 2048, 8192, 16);
    reduce_sk<<<dim3(32,16),256,0,stream>>>(gpart, 8192, 32, bfc, nullptr, act, 2);
    // 7. OUT + residual -> f32 d_out (K=8192, N=2048, splitk=64, kchunk=128)
    gemm_sk<128><<<4*64,256,0,stream>>>(act, Wout, gpart, 8192, 2048, 4);
    reduce_sk<<<dim3(8,16),256,0,stream>>>(gpart, 2048, 64, bout, hbuf, (float*)d_out, 3);
    (void)in_sizes; (void)n_in; (void)out_size; (void)ws_size;
}

// Round 10
// 399.247 us; speedup vs baseline: 1.8538x; 1.1338x over previous
//
#include <hip/hip_runtime.h>
#include <hip/hip_bf16.h>

typedef unsigned int uint;

// B=16, H=2048, NH=16, HD=128, S=4096, 3H=6144, FF=8192. All tensors f32.
//
// Roofline note (measured this session, gfx950 container):
//   pure-read stream  ~3.07 TB/s  (probe_dense, FETCH=1.07GB/350us, R7)
//   pure-write stream ~6.7  TB/s  (harness fills)
//   read+write copy   ~6.3  TB/s total (guide m13) => read leg ~3.15 TB/s
// Attention reads KV = 1.07 GB at ~3.45 TB/s (~310 us) -> at the read ceiling.
// Whole pipeline = 399.5 us ~= attn(310) + weights(201MB@3.1=65) + partials(~17)
// + launches(~25) composed floor. NT loads regress (-13%, R9); restructures null.

// ---------------- LayerNorm (f32) ----------------
__global__ __launch_bounds__(256) void ln_f32_kernel(const float* __restrict__ in,
    const float* __restrict__ g, const float* __restrict__ bb, float* __restrict__ out)
{
    int row = blockIdx.x, t = threadIdx.x;
    const float* rp = in + row*2048;
    float4 a = ((const float4*)rp)[2*t];
    float4 b = ((const float4*)rp)[2*t+1];
    float v[8] = {a.x,a.y,a.z,a.w,b.x,b.y,b.z,b.w};
    float s=0.f, s2=0.f;
    #pragma unroll
    for(int i=0;i<8;i++){ s+=v[i]; s2+=v[i]*v[i]; }
    #pragma unroll
    for(int o=32;o>0;o>>=1){ s += __shfl_xor(s,o); s2 += __shfl_xor(s2,o); }
    __shared__ float red[8];
    int wv=t>>6, ln=t&63;
    if(ln==0){ red[wv]=s; red[4+wv]=s2; }
    __syncthreads();
    s  = red[0]+red[1]+red[2]+red[3];
    s2 = red[4]+red[5]+red[6]+red[7];
    float mu = s*(1.f/2048.f);
    float var = s2*(1.f/2048.f) - mu*mu;
    float rs = rsqrtf(var + 1e-5f);
    float4 g0 = ((const float4*)g)[2*t],  g1 = ((const float4*)g)[2*t+1];
    float4 b0 = ((const float4*)bb)[2*t], b1 = ((const float4*)bb)[2*t+1];
    float* op = out + row*2048 + t*8;
    float4 o0 = make_float4((v[0]-mu)*rs*g0.x+b0.x, (v[1]-mu)*rs*g0.y+b0.y,
                            (v[2]-mu)*rs*g0.z+b0.z, (v[3]-mu)*rs*g0.w+b0.w);
    float4 o1 = make_float4((v[4]-mu)*rs*g1.x+b1.x, (v[5]-mu)*rs*g1.y+b1.y,
                            (v[6]-mu)*rs*g1.z+b1.z, (v[7]-mu)*rs*g1.w+b1.w);
    ((float4*)op)[0]=o0; ((float4*)op)[1]=o1;
}

// ---------------- split-K skinny GEMM: part[kc][16][N] = X[16,K] * W[K,N] ----------------
template<int KCHUNK>
__global__ __launch_bounds__(256) void gemm_sk(const float* __restrict__ X,
    const float* __restrict__ W, float* __restrict__ part, int K, int N, int colchunks)
{
    __shared__ float XS[16][KCHUNK];
    int cc = blockIdx.x % colchunks;
    int kc = blockIdx.x / colchunks;
    int k0 = kc * KCHUNK;
    for (int idx = threadIdx.x; idx < 16*KCHUNK; idx += 256){
        int m = idx / KCHUNK, i = idx % KCHUNK;
        XS[m][i] = X[m*K + k0 + i];
    }
    __syncthreads();
    int n0 = cc*512 + threadIdx.x*2;
    float a0[16], a1[16];
    #pragma unroll
    for(int m=0;m<16;m++){ a0[m]=0.f; a1[m]=0.f; }
    const float* Wp = W + (size_t)k0*N + n0;
    for (int i=0;i<KCHUNK;i+=4){
        float2 w0 = *(const float2*)(Wp + (size_t)(i+0)*N);
        float2 w1 = *(const float2*)(Wp + (size_t)(i+1)*N);
        float2 w2 = *(const float2*)(Wp + (size_t)(i+2)*N);
        float2 w3 = *(const float2*)(Wp + (size_t)(i+3)*N);
        #pragma unroll
        for(int m=0;m<16;m++){
            float4 x4 = *(const float4*)&XS[m][i];
            a0[m] += x4.x*w0.x + x4.y*w1.x + x4.z*w2.x + x4.w*w3.x;
            a1[m] += x4.x*w0.y + x4.y*w1.y + x4.z*w2.y + x4.w*w3.y;
        }
    }
    #pragma unroll
    for(int m=0;m<16;m++){
        *(float2*)&part[((size_t)(kc*16+m))*N + n0] = make_float2(a0[m], a1[m]);
    }
}

// ---------------- split-K reduce + bias + (residual / gelu / store) ----------------
__global__ __launch_bounds__(256) void reduce_sk(const float* __restrict__ part, int N, int splitk,
    const float* __restrict__ bias, const float* __restrict__ res,
    float* __restrict__ outf, int mode)
{
    int n = blockIdx.x*256 + threadIdx.x;
    int m = blockIdx.y;
    size_t stride = (size_t)16*N;
    const float* p = part + (size_t)m*N + n;
    float s = 0.f;
    for (int kc=0;kc<splitk;kc++) s += p[(size_t)kc*stride];
    s += bias[n];
    if (mode==1 || mode==3) s += res[m*N+n];
    if (mode==2){
        float x = s;
        float t = tanhf(0.7978845608028654f*(x + 0.044715f*x*x*x));
        s = 0.5f*x*(1.f+t);
    }
    outf[m*N+n] = s;
}

// ---------------- flash-decode attention, phase-split K then V ----------------
__global__ __launch_bounds__(256) void attn_chunk(const float* __restrict__ qkv,
    const float* __restrict__ Kc, const float* __restrict__ Vc, float* __restrict__ part)
{
    int h = blockIdx.y, b = blockIdx.z;
    int wave = threadIdx.x >> 6, lane = threadIdx.x & 63;
    int wc = blockIdx.x*4 + wave;            // 0..31
    int grp = lane >> 4, cl = lane & 15;
    const float* qrow = qkv + b*6144 + h*128 + cl*8;
    float4 qa = *(const float4*)qrow;
    float4 qb = *(const float4*)(qrow + 4);
    size_t bh = (size_t)(b*16+h);
    size_t base = bh*524288 + (size_t)wc*16384 + (size_t)grp*128 + cl*8;
    const float* Kp = Kc + base;
    const float* Vp = Vc + base;

    float s[32];
    #pragma unroll
    for (int i=0;i<32;i++){
        const float* kp = Kp + (size_t)i*512;
        float4 ka = *(const float4*)kp;
        float4 kb = *(const float4*)(kp + 4);
        float p = qa.x*ka.x + qa.y*ka.y + qa.z*ka.z + qa.w*ka.w
                + qb.x*kb.x + qb.y*kb.y + qb.z*kb.z + qb.w*kb.w;
        p += __shfl_xor(p,1); p += __shfl_xor(p,2);
        p += __shfl_xor(p,4); p += __shfl_xor(p,8);
        s[i] = p * 0.08838834764831845f;
    }
    float m = s[0];
    #pragma unroll
    for (int i=1;i<32;i++) m = fmaxf(m, s[i]);
    m = fmaxf(m, __shfl_xor(m,16));
    m = fmaxf(m, __shfl_xor(m,32));

    float sn = 0.f;
    if (wc == 31){
        const float* kn = qkv + b*6144 + 2048 + h*128 + cl*8;
        float4 ka = *(const float4*)kn, kb = *(const float4*)(kn+4);
        float p = qa.x*ka.x + qa.y*ka.y + qa.z*ka.z + qa.w*ka.w
                + qb.x*kb.x + qb.y*kb.y + qb.z*kb.z + qb.w*kb.w;
        p += __shfl_xor(p,1); p += __shfl_xor(p,2);
        p += __shfl_xor(p,4); p += __shfl_xor(p,8);
        sn = p * 0.08838834764831845f;
        m = fmaxf(m, sn);
    }

    float l = 0.f;
    #pragma unroll
    for (int i=0;i<32;i++){ s[i] = __expf(s[i] - m); l += s[i]; }

    float o[8];
    #pragma unroll
    for (int i=0;i<8;i++) o[i] = 0.f;
    #pragma unroll
    for (int i=0;i<32;i++){
        const float* vp = Vp + (size_t)i*512;
        float4 va = *(const float4*)vp;
        float4 vb = *(const float4*)(vp + 4);
        float e = s[i];
        o[0]+=e*va.x; o[1]+=e*va.y; o[2]+=e*va.z; o[3]+=e*va.w;
        o[4]+=e*vb.x; o[5]+=e*vb.y; o[6]+=e*vb.z; o[7]+=e*vb.w;
    }
    if (wc == 31){
        const float* vn = qkv + b*6144 + 4096 + h*128 + cl*8;
        float4 va = *(const float4*)vn, vb = *(const float4*)(vn+4);
        float e = (grp==0) ? __expf(sn - m) : 0.f;
        l += e;
        o[0]+=e*va.x; o[1]+=e*va.y; o[2]+=e*va.z; o[3]+=e*va.w;
        o[4]+=e*vb.x; o[5]+=e*vb.y; o[6]+=e*vb.z; o[7]+=e*vb.w;
    }

    l += __shfl_xor(l,16); l += __shfl_xor(l,32);
    #pragma unroll
    for(int i=0;i<8;i++){ o[i] += __shfl_xor(o[i],16); o[i] += __shfl_xor(o[i],32); }
    float* pp = part + ((size_t)bh*32 + wc)*136;
    if (lane==0){ pp[0]=m; pp[1]=l; }
    if (lane<16){
        *(float4*)&pp[4 + lane*8]     = make_float4(o[0],o[1],o[2],o[3]);
        *(float4*)&pp[4 + lane*8 + 4] = make_float4(o[4],o[5],o[6],o[7]);
    }
}

__global__ __launch_bounds__(64) void attn_combine(const float* __restrict__ part,
                                                   float* __restrict__ attn_out)
{
    int bh = blockIdx.x;      // 0..255
    int lane = threadIdx.x;   // 64
    const float* pp = part + (size_t)bh*32*136;
    float M = -1e30f;
    for (int kc=0;kc<32;kc++) M = fmaxf(M, pp[kc*136]);
    float den=0.f, a0=0.f, a1=0.f;
    for (int kc=0;kc<32;kc++){
        float f = __expf(pp[kc*136] - M);
        den += f * pp[kc*136+1];
        float2 o = *(const float2*)&pp[kc*136 + 4 + 2*lane];
        a0 += f*o.x; a1 += f*o.y;
    }
    float inv = 1.f/den;
    int b = bh>>4, h = bh&15;
    float* op = attn_out + b*2048 + h*128 + 2*lane;
    op[0]=a0*inv; op[1]=a1*inv;
}

extern "C" void kernel_launch(void* const* d_in, const int* in_sizes, int n_in,
                              void* d_out, int out_size, void* d_ws, size_t ws_size,
                              hipStream_t stream)
{
    const float* hid  = (const float*)d_in[0];
    const float* Kc   = (const float*)d_in[1];
    const float* Vc   = (const float*)d_in[2];
    const float* ln1g = (const float*)d_in[3];
    const float* ln1b = (const float*)d_in[4];
    const float* Wqkv = (const float*)d_in[5];
    const float* bqkv = (const float*)d_in[6];
    const float* Wproj= (const float*)d_in[7];
    const float* bproj= (const float*)d_in[8];
    const float* ln2g = (const float*)d_in[9];
    const float* ln2b = (const float*)d_in[10];
    const float* Wfc  = (const float*)d_in[11];
    const float* bfc  = (const float*)d_in[12];
    const float* Wout = (const float*)d_in[13];
    const float* bout = (const float*)d_in[14];

    float* ws      = (float*)d_ws;
    float* xln     = ws;                    // 32768
    float* qkv     = xln + 32768;           // 98304
    float* attn_o  = qkv + 98304;           // 32768
    float* hbuf    = attn_o + 32768;        // 32768
    float* yln     = hbuf + 32768;          // 32768
    float* act     = yln + 32768;           // 131072
    float* apart   = act + 131072;          // 16*16*32*136 = 1114112
    float* gpart   = apart + 1114112;       // up to 3145728 (QKV partials)

    // 1. LN1
    ln_f32_kernel<<<16,256,0,stream>>>(hid, ln1g, ln1b, xln);
    // 2. QKV = xln @ Wqkv + b   (K=2048, N=6144, splitk=32)
    gemm_sk<64><<<12*32,256,0,stream>>>(xln, Wqkv, gpart, 2048, 6144, 12);
    reduce_sk<<<dim3(24,16),256,0,stream>>>(gpart, 6144, 32, bqkv, nullptr, qkv, 0);
    // 3. attention
    attn_chunk<<<dim3(8,16,16),256,0,stream>>>(qkv, Kc, Vc, apart);
    attn_combine<<<256,64,0,stream>>>(apart, attn_o);
    // 4. proj + residual (K=2048, N=2048, splitk=32)
    gemm_sk<64><<<4*32,256,0,stream>>>(attn_o, Wproj, gpart, 2048, 2048, 4);
    reduce_sk<<<dim3(8,16),256,0,stream>>>(gpart, 2048, 32, bproj, hid, hbuf, 1);
    // 5. LN2
    ln_f32_kernel<<<16,256,0,stream>>>(hbuf, ln2g, ln2b, yln);
    // 6. FC + gelu (K=2048, N=8192, splitk=32)
    gemm_sk<64><<<16*32,256,0,stream>>>(yln, Wfc, gpart, 2048, 8192, 16);
    reduce_sk<<<dim3(32,16),256,0,stream>>>(gpart, 8192, 32, bfc, nullptr, act, 2);
    // 7. OUT + residual -> f32 d_out (K=8192, N=2048, splitk=64, kchunk=128)
    gemm_sk<128><<<4*64,256,0,stream>>>(act, Wout, gpart, 8192, 2048, 4);
    reduce_sk<<<dim3(8,16),256,0,stream>>>(gpart, 2048, 64, bout, hbuf, (float*)d_out, 3);
    (void)in_sizes; (void)n_in; (void)out_size; (void)ws_size;
}